// Round 5
// baseline (83.562 us; speedup 1.0000x reference)
//
#include <hip/hip_runtime.h>
#include <hip/hip_bf16.h>
#include <stdint.h>

typedef __attribute__((ext_vector_type(4))) int   i32x4;
typedef __attribute__((ext_vector_type(8))) int   i32x8;
typedef __attribute__((ext_vector_type(4))) float f32x4;
typedef __attribute__((ext_vector_type(2))) unsigned int u32x2;

#define MDIM   4096
#define NDIM   4096
#define KBYTES 2048   // K=4096 fp4 elems -> 2048 packed bytes per row
#define NKBLK  128    // K/32 scale blocks per row

#define BM   256
#define BN   256
#define BKB  128                 // K-bytes per tile (= 256 fp4 elems = 8 scale blocks)
#define KT   (KBYTES / BKB)      // 16 K-tiles

#define BARF()  asm volatile("s_barrier" ::: "memory")
#define LGKM0() asm volatile("s_waitcnt lgkmcnt(0)" ::: "memory")
// Counted drain (T4): ALWAYS leave the newest 6-op group (kt+2.kw0) in flight.
#define VMC6()  asm volatile("s_waitcnt vmcnt(6)" ::: "memory")

// ---------------- repack: int32-per-byte -> packed bytes ----------------
__global__ void repack_bytes(const int* __restrict__ a, const int* __restrict__ b,
                             uint32_t* __restrict__ ap, uint32_t* __restrict__ bp) {
  const size_t n4 = (size_t)MDIM * KBYTES / 4;
  for (size_t i = (size_t)blockIdx.x * blockDim.x + threadIdx.x; i < n4;
       i += (size_t)gridDim.x * blockDim.x) {
    i32x4 va = *(const i32x4*)(a + i * 4);
    ap[i] = (uint32_t)(va.x & 255) | ((uint32_t)(va.y & 255) << 8) |
            ((uint32_t)(va.z & 255) << 16) | ((uint32_t)(va.w & 255) << 24);
    i32x4 vb = *(const i32x4*)(b + i * 4);
    bp[i] = (uint32_t)(vb.x & 255) | ((uint32_t)(vb.y & 255) << 8) |
            ((uint32_t)(vb.z & 255) << 16) | ((uint32_t)(vb.w & 255) << 24);
  }
}

// -------- scales: float biased-exp -> uint8 E8M0, layout [kb][m&15][m>>4] ------
__global__ void repack_scales(const float* __restrict__ sa, const float* __restrict__ sb,
                              uint8_t* __restrict__ sat, uint8_t* __restrict__ sbt) {
  int t = blockIdx.x * blockDim.x + threadIdx.x;
  if (t >= MDIM * NKBLK) return;
  int m  = t >> 7;     // row
  int kb = t & 127;    // k-block
  int o  = kb * 4096 + (m & 15) * 256 + (m >> 4);
  sat[o] = (uint8_t)(int)sa[t];
  sbt[o] = (uint8_t)(int)sb[t];
}

__device__ __forceinline__ i32x8 frag8(i32x4 v) {
  i32x8 r = {v.x, v.y, v.z, v.w, 0, 0, 0, 0};
  return r;
}

__device__ __forceinline__ int sbyte2(u32x2 p, int i) {
  return (int)((i < 4 ? (p.x >> (i * 8)) : (p.y >> ((i - 4) * 8))) & 0xffu);
}

// ---- MXFP4 GEMM, 256x256 tile, 8 waves, kw-half double-buffer + counted vmcnt ----
// LDS: [buf(2)][mat(2)][kw(2)][row(256)][64B]  = 128 KB.
// kw-half h of tile kt is staged 1.5-2 tiles ahead; tile-end wait = vmcnt(6).
__global__ __launch_bounds__(512, 2) void mxfp4_gemm(
    const uint8_t* __restrict__ ap, const uint8_t* __restrict__ bp,
    const uint8_t* __restrict__ sat, const uint8_t* __restrict__ sbt,
    float* __restrict__ out) {
  extern __shared__ uint8_t lds[];

  const int tid  = threadIdx.x;
  const int lane = tid & 63;
  const int w    = tid >> 6;        // wave 0..7
  const int wrow = w >> 2;          // 2 M-waves
  const int wcol = w & 3;           // 4 N-waves
  const int g    = lane >> 4;       // k-group 0..3 (32 fp4 elems each)
  const int l15  = lane & 15;

  const int bx = blockIdx.x;
  const int by = blockIdx.y;

  const uint8_t* aBase = ap + (size_t)(by * BM) * KBYTES;
  const uint8_t* bBase = bp + (size_t)(bx * BN) * KBYTES;

  // --- swizzle: LDS[row][sp] holds global 16B-slot sp ^ ((row>>1)&3) ----------
  // read side: slot for k-group g of row R is g ^ ((R>>1)&3) = g ^ ((l15>>1)&3)
  const int rdslot = (g ^ ((l15 >> 1) & 3)) * 16;
  // stage side: lane -> row arow0+c*16+(lane>>2), sp=lane&3; source pre-swizzled
  const int sr = lane >> 2, sp = lane & 3;
  const int soff4 = sr * KBYTES + ((sp ^ ((sr >> 1) & 3)) * 16);
  const int arow0 = w * 32;         // each wave stages 32 A-rows + 32 B-rows

#define PLANE(bufi, mat, kwX) (lds + (bufi) * 65536 + (mat) * 32768 + (kwX) * 16384)

  // stage one kw-half (64B of K) of tile ktX into buffer bufi: 4 vm ops
#define STAGE_HALF(bufi, ktX, kwX)                                                        \
  do {                                                                                    \
    const uint8_t* _sa = aBase + (size_t)arow0 * KBYTES + (ktX) * BKB + (kwX) * 64 + soff4; \
    const uint8_t* _sb = bBase + (size_t)arow0 * KBYTES + (ktX) * BKB + (kwX) * 64 + soff4; \
    uint8_t* _da = PLANE(bufi, 0, kwX) + arow0 * 64;                                      \
    uint8_t* _db = PLANE(bufi, 1, kwX) + arow0 * 64;                                      \
    __builtin_amdgcn_global_load_lds((__attribute__((address_space(1))) void*)_sa,        \
        (__attribute__((address_space(3))) void*)_da, 16, 0, 0);                          \
    __builtin_amdgcn_global_load_lds((__attribute__((address_space(1))) void*)(_sa + 16 * KBYTES), \
        (__attribute__((address_space(3))) void*)(_da + 1024), 16, 0, 0);                 \
    __builtin_amdgcn_global_load_lds((__attribute__((address_space(1))) void*)_sb,        \
        (__attribute__((address_space(3))) void*)(_db), 16, 0, 0);                        \
    __builtin_amdgcn_global_load_lds((__attribute__((address_space(1))) void*)(_sb + 16 * KBYTES), \
        (__attribute__((address_space(3))) void*)(_db + 1024), 16, 0, 0);                 \
  } while (0)

  // scale pointers (layout [kb][m&15][m>>4]); kb = kt*8 + kw*4 + g
  const uint8_t* sAp = sat + (size_t)l15 * 256 + by * 16 + wrow * 8;
  const uint8_t* sBp = sbt + (size_t)l15 * 256 + bx * 16 + wcol * 4;

  f32x4 acc[8][4] = {};
  i32x4 a0[4], a1[4], bf[4];
  // scale registers: kw0 needs 3 generations (staged 2 tiles ahead), kw1 needs 2
  u32x2 sA0c, sA0m, sA0n, sA1c, sA1n;
  uint32_t sB0c, sB0m, sB0n, sB1c, sB1n;

  // ---------------- prologue: kt0.kw0 | kt0.kw1 | kt1.kw0, then vmcnt(6) ----------
  STAGE_HALF(0, 0, 0);
  sA0c = *(const u32x2*)(sAp + (size_t)(0 * 8 + 0 + g) * 4096);
  sB0c = *(const uint32_t*)(sBp + (size_t)(0 * 8 + 0 + g) * 4096);
  STAGE_HALF(0, 0, 1);
  sA1c = *(const u32x2*)(sAp + (size_t)(0 * 8 + 4 + g) * 4096);
  sB1c = *(const uint32_t*)(sBp + (size_t)(0 * 8 + 4 + g) * 4096);
  STAGE_HALF(1, 1, 0);
  sA0m = *(const u32x2*)(sAp + (size_t)(1 * 8 + 0 + g) * 4096);
  sB0m = *(const uint32_t*)(sBp + (size_t)(1 * 8 + 0 + g) * 4096);
  VMC6();          // kt0 fully landed; kt1.kw0 still in flight
  BARF();

  for (int kt = 0; kt < KT; ++kt) {
    const int cur = kt & 1;
    const int nxt = cur ^ 1;
    const uint8_t* A0 = PLANE(cur, 0, 0);
    const uint8_t* B0 = PLANE(cur, 1, 0);
    const uint8_t* A1p = PLANE(cur, 0, 1);
    const uint8_t* B1p = PLANE(cur, 1, 1);
    const int kt1 = (kt + 1) & (KT - 1);   // modulo: last tiles stage junk into dead planes
    const int kt2 = (kt + 2) & (KT - 1);

    // ===== P0: reads kw0 (bf + a0..3); issue {kt+1.kw1 stages + scales} ==========
#pragma unroll
    for (int ns = 0; ns < 4; ++ns)
      bf[ns] = *(const i32x4*)(B0 + (wcol * 64 + ns * 16 + l15) * 64 + rdslot);
#pragma unroll
    for (int ms = 0; ms < 4; ++ms)
      a0[ms] = *(const i32x4*)(A0 + (wrow * 128 + ms * 16 + l15) * 64 + rdslot);
    STAGE_HALF(nxt, kt1, 1);
    sA1n = *(const u32x2*)(sAp + (size_t)(kt1 * 8 + 4 + g) * 4096);
    sB1n = *(const uint32_t*)(sBp + (size_t)(kt1 * 8 + 4 + g) * 4096);
    BARF();
    LGKM0();
    __builtin_amdgcn_s_setprio(1);
#pragma unroll
    for (int ms = 0; ms < 4; ++ms) {
      const int sa = sbyte2(sA0c, ms);
#pragma unroll
      for (int ns = 0; ns < 4; ++ns)
        acc[ms][ns] = __builtin_amdgcn_mfma_scale_f32_16x16x128_f8f6f4(
            frag8(a0[ms]), frag8(bf[ns]), acc[ms][ns], 4, 4,
            0, sa, 0, (int)((sB0c >> (ns * 8)) & 0xffu));
    }
    __builtin_amdgcn_s_setprio(0);
    BARF();

    // ===== P1: reads kw0 (a4..7) ================================================
#pragma unroll
    for (int ms = 0; ms < 4; ++ms)
      a1[ms] = *(const i32x4*)(A0 + (wrow * 128 + (ms + 4) * 16 + l15) * 64 + rdslot);
    BARF();
    LGKM0();
    __builtin_amdgcn_s_setprio(1);
#pragma unroll
    for (int ms = 0; ms < 4; ++ms) {
      const int sa = sbyte2(sA0c, ms + 4);
#pragma unroll
      for (int ns = 0; ns < 4; ++ns)
        acc[ms + 4][ns] = __builtin_amdgcn_mfma_scale_f32_16x16x128_f8f6f4(
            frag8(a1[ms]), frag8(bf[ns]), acc[ms + 4][ns], 4, 4,
            0, sa, 0, (int)((sB0c >> (ns * 8)) & 0xffu));
    }
    __builtin_amdgcn_s_setprio(0);
    BARF();

    // ===== P2: reads kw1 (bf + a0..3); issue {kt+2.kw0 stages + scales} ==========
    // cur.kw0 reads all drained by P1's LGKM0 + barrier -> safe to overwrite.
#pragma unroll
    for (int ns = 0; ns < 4; ++ns)
      bf[ns] = *(const i32x4*)(B1p + (wcol * 64 + ns * 16 + l15) * 64 + rdslot);
#pragma unroll
    for (int ms = 0; ms < 4; ++ms)
      a0[ms] = *(const i32x4*)(A1p + (wrow * 128 + ms * 16 + l15) * 64 + rdslot);
    STAGE_HALF(cur, kt2, 0);
    sA0n = *(const u32x2*)(sAp + (size_t)(kt2 * 8 + 0 + g) * 4096);
    sB0n = *(const uint32_t*)(sBp + (size_t)(kt2 * 8 + 0 + g) * 4096);
    BARF();
    LGKM0();
    __builtin_amdgcn_s_setprio(1);
#pragma unroll
    for (int ms = 0; ms < 4; ++ms) {
      const int sa = sbyte2(sA1c, ms);
#pragma unroll
      for (int ns = 0; ns < 4; ++ns)
        acc[ms][ns] = __builtin_amdgcn_mfma_scale_f32_16x16x128_f8f6f4(
            frag8(a0[ms]), frag8(bf[ns]), acc[ms][ns], 4, 4,
            0, sa, 0, (int)((sB1c >> (ns * 8)) & 0xffu));
    }
    __builtin_amdgcn_s_setprio(0);
    BARF();

    // ===== P3: reads kw1 (a4..7); rotate scales; COUNTED drain vmcnt(6) ==========
#pragma unroll
    for (int ms = 0; ms < 4; ++ms)
      a1[ms] = *(const i32x4*)(A1p + (wrow * 128 + (ms + 4) * 16 + l15) * 64 + rdslot);
    BARF();
    LGKM0();
    __builtin_amdgcn_s_setprio(1);
#pragma unroll
    for (int ms = 0; ms < 4; ++ms) {
      const int sa = sbyte2(sA1c, ms + 4);
#pragma unroll
      for (int ns = 0; ns < 4; ++ns)
        acc[ms + 4][ns] = __builtin_amdgcn_mfma_scale_f32_16x16x128_f8f6f4(
            frag8(a1[ms]), frag8(bf[ns]), acc[ms + 4][ns], 4, 4,
            0, sa, 0, (int)((sB1c >> (ns * 8)) & 0xffu));
    }
    __builtin_amdgcn_s_setprio(0);
    sA0c = sA0m; sB0c = sB0m; sA0m = sA0n; sB0m = sB0n;
    sA1c = sA1n; sB1c = sB1n;
    // outstanding (oldest->newest): [kt+1.kw1 grp(6)] [kt+2.kw0 grp(6)].
    // vmcnt(6): kt+1 fully drained, kt+2.kw0 stays in flight (T4 counted wait).
    VMC6();
    BARF();
  }

  // epilogue: D mapping row=(lane>>4)*4+r, col=lane&15 per 16x16 block
  float* ob = out + (size_t)(by * BM + wrow * 128) * NDIM + bx * BN + wcol * 64;
#pragma unroll
  for (int ms = 0; ms < 8; ++ms)
#pragma unroll
    for (int ns = 0; ns < 4; ++ns) {
#pragma unroll
      for (int r = 0; r < 4; ++r)
        ob[(size_t)(ms * 16 + g * 4 + r) * NDIM + ns * 16 + l15] = acc[ms][ns][r];
    }
#undef STAGE_HALF
#undef PLANE
}

extern "C" void kernel_launch(void* const* d_in, const int* in_sizes, int n_in,
                              void* d_out, int out_size, void* d_ws, size_t ws_size,
                              hipStream_t stream) {
  (void)in_sizes; (void)n_in; (void)out_size; (void)ws_size;
  const int*   a  = (const int*)d_in[0];
  const int*   b  = (const int*)d_in[1];
  const float* sa = (const float*)d_in[2];
  const float* sb = (const float*)d_in[3];
  float* out = (float*)d_out;

  uint8_t* ws = (uint8_t*)d_ws;
  uint32_t* ap = (uint32_t*)ws;                          // 8 MB packed A
  uint32_t* bp = (uint32_t*)(ws + (8u << 20));           // 8 MB packed B
  uint8_t*  sat = ws + (16u << 20);                      // 512 KB scales A
  uint8_t*  sbt = ws + (16u << 20) + (512u << 10);       // 512 KB scales B

  repack_bytes<<<2048, 256, 0, stream>>>(a, b, ap, bp);
  repack_scales<<<(MDIM * NKBLK + 255) / 256, 256, 0, stream>>>(sa, sb, sat, sbt);

  hipFuncSetAttribute((const void*)mxfp4_gemm,
                      hipFuncAttributeMaxDynamicSharedMemorySize, 131072);

  dim3 grid(NDIM / BN, MDIM / BM);   // 16 x 16 = 256 blocks = 1/CU
  mxfp4_gemm<<<grid, 512, 131072, stream>>>((const uint8_t*)ap, (const uint8_t*)bp,
                                            sat, sbt, out);
}